// Round 1
// baseline (749.221 us; speedup 1.0000x reference)
//
#include <hip/hip_runtime.h>
#include <hip/hip_bf16.h>
#include <math.h>

#define BB   2
#define SS   1024
#define HIDD 768
#define NHH  12
#define HDD  64

__device__ __forceinline__ float wave_max64(float x) {
#pragma unroll
  for (int off = 32; off > 0; off >>= 1) x = fmaxf(x, __shfl_xor(x, off, 64));
  return x;
}
__device__ __forceinline__ float wave_sum64(float x) {
#pragma unroll
  for (int off = 32; off > 0; off >>= 1) x += __shfl_xor(x, off, 64);
  return x;
}

// ---------------------------------------------------------------------------
// Kernel 1: QKV projection GEMM. X[2048,768] @ W[768,768] + b, stored as
// [B, NH, S, HD] (head-major) into ws. grid.z selects q/k/v.
// ---------------------------------------------------------------------------
__global__ __launch_bounds__(256) void qkv_gemm_kernel(
    const float* __restrict__ X,
    const float* __restrict__ Wq, const float* __restrict__ bq,
    const float* __restrict__ Wk, const float* __restrict__ bk,
    const float* __restrict__ Wv, const float* __restrict__ bv,
    float* __restrict__ ws) {
  const int zi = blockIdx.z;
  const float* __restrict__ W    = (zi == 0) ? Wq : (zi == 1 ? Wk : Wv);
  const float* __restrict__ bias = (zi == 0) ? bq : (zi == 1 ? bk : bv);
  float* __restrict__ O = ws + (size_t)zi * ((size_t)BB * NHH * SS * HDD);

  const int bm = blockIdx.y * 64;
  const int bn = blockIdx.x * 64;
  const int tid = threadIdx.x;
  const int tx = tid & 15, ty = tid >> 4;

  __shared__ float As[16][68];  // [k][m], 68-stride => 16B-aligned rows
  __shared__ float Bs[16][68];  // [k][n]

  float acc[4][4] = {};

  const int arow = tid >> 2;
  const int akc  = (tid & 3) << 2;
  const int brow = tid >> 4;
  const int bcol = (tid & 15) << 2;

  for (int k0 = 0; k0 < HIDD; k0 += 16) {
    float4 a4 = *(const float4*)&X[(size_t)(bm + arow) * HIDD + k0 + akc];
    float4 b4 = *(const float4*)&W[(size_t)(k0 + brow) * HIDD + bn + bcol];
    As[akc + 0][arow] = a4.x;
    As[akc + 1][arow] = a4.y;
    As[akc + 2][arow] = a4.z;
    As[akc + 3][arow] = a4.w;
    *(float4*)&Bs[brow][bcol] = b4;
    __syncthreads();
#pragma unroll
    for (int kk = 0; kk < 16; ++kk) {
      float4 av  = *(const float4*)&As[kk][ty << 2];
      float4 bv4 = *(const float4*)&Bs[kk][tx << 2];
      float a[4]  = {av.x, av.y, av.z, av.w};
      float bb[4] = {bv4.x, bv4.y, bv4.z, bv4.w};
#pragma unroll
      for (int i = 0; i < 4; ++i)
#pragma unroll
        for (int j = 0; j < 4; ++j) acc[i][j] = fmaf(a[i], bb[j], acc[i][j]);
    }
    __syncthreads();
  }

  const int h = bn >> 6;  // BN=64 == HD, so one head per block-column
#pragma unroll
  for (int i = 0; i < 4; ++i) {
    int m = bm + (ty << 2) + i;
    int bidx = m >> 10;
    int srow = m & 1023;
    int d0 = tx << 2;
    float4 o;
    o.x = acc[i][0] + bias[bn + d0 + 0];
    o.y = acc[i][1] + bias[bn + d0 + 1];
    o.z = acc[i][2] + bias[bn + d0 + 2];
    o.w = acc[i][3] + bias[bn + d0 + 3];
    *(float4*)&O[(((size_t)(bidx * NHH + h)) * SS + srow) * HDD + d0] = o;
  }
}

// ---------------------------------------------------------------------------
// Kernel 2: fused dual-branch flash attention with Toeplitz positional bias.
// One block = (b, h, 16 q-rows). K-tiles of 64. 4 waves, wave w owns q-rows
// 4w..4w+3; lane = k-column (score phase) / d (PV phase).
// ---------------------------------------------------------------------------
__global__ __launch_bounds__(256) void attn_kernel(
    const float* __restrict__ ws,
    const float* __restrict__ am,     // attention_mask  [B, S]
    const float* __restrict__ smask,  // scaled mask     [S, S]
    const float* __restrict__ selp,   // selector        [B, S]
    const float* __restrict__ demb,   // dist_emb        [2047, 64]
    float* __restrict__ out) {        // [B, S, 768]
  const int l0 = blockIdx.x * 16;
  const int h  = blockIdx.y;
  const int b  = blockIdx.z;
  const size_t hsz = (size_t)BB * NHH * SS * HDD;
  const size_t hb  = ((size_t)b * NHH + h) * SS * HDD;
  const float* __restrict__ qb = ws + hb;
  const float* __restrict__ kb = ws + hsz + hb;
  const float* __restrict__ vb = ws + 2 * hsz + hb;

  // stride 68 floats = 272B = 17*16B: b128 row reads with lane=row are
  // conflict-free-optimal; broadcasts are free.
  __shared__ float qs[16][68];
  __shared__ float ks[64][68];
  __shared__ float vs[64][68];
  __shared__ float es[79][68];
  __shared__ float ps1[16][68];
  __shared__ float ps2[16][68];

  const int tid  = threadIdx.x;
  const int lane = tid & 63;
  const int w    = tid >> 6;

  {  // stage q tile (16 x 64)
    int row = tid >> 4;
    int c = (tid & 15) << 2;
    *(float4*)&qs[row][c] = *(const float4*)&qb[(size_t)(l0 + row) * HDD + c];
  }

  float m1[4], m2[4], sum1[4], sum2[4], acc1[4], acc2[4];
#pragma unroll
  for (int i = 0; i < 4; ++i) {
    m1[i] = -INFINITY; m2[i] = -INFINITY;
    sum1[i] = 0.f; sum2[i] = 0.f;
    acc1[i] = 0.f; acc2[i] = 0.f;
  }

  for (int r0 = 0; r0 < SS; r0 += 64) {
    __syncthreads();  // prev-iter readers done (also fences q staging, iter 0)
    for (int i = tid; i < 64 * 16; i += 256) {
      int row = i >> 4;
      int c = (i & 15) << 2;
      *(float4*)&ks[row][c] = *(const float4*)&kb[(size_t)(r0 + row) * HDD + c];
      *(float4*)&vs[row][c] = *(const float4*)&vb[(size_t)(r0 + row) * HDD + c];
    }
    // dist_emb rows needed this tile: global rows ebase..ebase+78
    const int ebase = l0 - r0 + 960;
    for (int i = tid; i < 79 * 16; i += 256) {
      int row = i >> 4;
      int c = (i & 15) << 2;
      *(float4*)&es[row][c] = *(const float4*)&demb[(size_t)(ebase + row) * HDD + c];
    }
    __syncthreads();

    const int r = lane;
    float qk[4] = {0.f, 0.f, 0.f, 0.f};
    float qp[4] = {0.f, 0.f, 0.f, 0.f};
#pragma unroll
    for (int c = 0; c < 64; c += 4) {
      float4 kv = *(const float4*)&ks[r][c];
#pragma unroll
      for (int i = 0; i < 4; ++i) {
        const int ll = (w << 2) + i;
        float4 qv = *(const float4*)&qs[ll][c];
        float4 ev = *(const float4*)&es[ll - r + 63][c];  // e = l_loc - r_loc + 63
        qk[i] = fmaf(qv.x, kv.x, qk[i]); qk[i] = fmaf(qv.y, kv.y, qk[i]);
        qk[i] = fmaf(qv.z, kv.z, qk[i]); qk[i] = fmaf(qv.w, kv.w, qk[i]);
        qp[i] = fmaf(qv.x, ev.x, qp[i]); qp[i] = fmaf(qv.y, ev.y, qp[i]);
        qp[i] = fmaf(qv.z, ev.z, qp[i]); qp[i] = fmaf(qv.w, ev.w, qp[i]);
      }
    }

    const float amr = am[(b << 10) + r0 + r];
#pragma unroll
    for (int i = 0; i < 4; ++i) {
      const int ll = (w << 2) + i;
      const float smv = smask[(size_t)(l0 + ll) * SS + r0 + r];
      // scores (incl. mask), then local branch re-adds mask (faithful to ref)
      const float s1 = (qk[i] + qp[i]) * 0.125f + amr;
      const float s2 = s1 * smv + amr;

      float t1 = wave_max64(s1);
      float mn1 = fmaxf(m1[i], t1);
      float e1 = __expf(m1[i] - mn1);
      float p1 = __expf(s1 - mn1);
      m1[i] = mn1;
      sum1[i] = sum1[i] * e1 + wave_sum64(p1);
      acc1[i] *= e1;
      ps1[ll][r] = p1;

      float t2 = wave_max64(s2);
      float mn2 = fmaxf(m2[i], t2);
      float e2 = __expf(m2[i] - mn2);
      float p2 = __expf(s2 - mn2);
      m2[i] = mn2;
      sum2[i] = sum2[i] * e2 + wave_sum64(p2);
      acc2[i] *= e2;
      ps2[ll][r] = p2;
    }
    __syncthreads();  // ps visible (wave-private, but keep ordering airtight)

    // PV: lane = d. ps reads broadcast; vs reads stride-1 (2-way, free).
#pragma unroll
    for (int rr = 0; rr < 64; rr += 4) {
      float pa[4][4], pb[4][4];
#pragma unroll
      for (int i = 0; i < 4; ++i) {
        float4 t1 = *(const float4*)&ps1[(w << 2) + i][rr];
        float4 t2 = *(const float4*)&ps2[(w << 2) + i][rr];
        pa[i][0] = t1.x; pa[i][1] = t1.y; pa[i][2] = t1.z; pa[i][3] = t1.w;
        pb[i][0] = t2.x; pb[i][1] = t2.y; pb[i][2] = t2.z; pb[i][3] = t2.w;
      }
#pragma unroll
      for (int j = 0; j < 4; ++j) {
        const float vv = vs[rr + j][lane];
#pragma unroll
        for (int i = 0; i < 4; ++i) {
          acc1[i] = fmaf(pa[i][j], vv, acc1[i]);
          acc2[i] = fmaf(pb[i][j], vv, acc2[i]);
        }
      }
    }
  }

#pragma unroll
  for (int i = 0; i < 4; ++i) {
    const int lg = l0 + (w << 2) + i;
    const float se = selp[(b << 10) + lg];
    const float o =
        se * (acc2[i] / sum2[i]) + (1.f - se) * (acc1[i] / sum1[i]);
    out[(((size_t)(b << 10) + lg) * NHH + h) * HDD + lane] = o;
  }
}

extern "C" void kernel_launch(void* const* d_in, const int* in_sizes, int n_in,
                              void* d_out, int out_size, void* d_ws, size_t ws_size,
                              hipStream_t stream) {
  const float* hidden = (const float*)d_in[0];
  const float* am     = (const float*)d_in[1];
  const float* smask  = (const float*)d_in[2];
  const float* selp   = (const float*)d_in[3];
  const float* Wq     = (const float*)d_in[4];
  const float* bq     = (const float*)d_in[5];
  const float* Wk     = (const float*)d_in[6];
  const float* bk     = (const float*)d_in[7];
  const float* Wv     = (const float*)d_in[8];
  const float* bv     = (const float*)d_in[9];
  const float* demb   = (const float*)d_in[10];
  float* out = (float*)d_out;
  float* ws  = (float*)d_ws;  // q,k,v each B*NH*S*HD f32 = 6.29MB; 18.9MB total

  dim3 g1(HIDD / 64, (BB * SS) / 64, 3);
  qkv_gemm_kernel<<<g1, 256, 0, stream>>>(hidden, Wq, bq, Wk, bk, Wv, bv, ws);

  dim3 g2(SS / 16, NHH, BB);
  attn_kernel<<<g2, 256, 0, stream>>>(ws, am, smask, selp, demb, out);
}

// Round 2
// 210.412 us; speedup vs baseline: 3.5607x; 3.5607x over previous
//
#include <hip/hip_runtime.h>
#include <hip/hip_bf16.h>
#include <math.h>

#define BB   2
#define SS   1024
#define HIDD 768
#define NHH  12
#define HDD  64

typedef float f32x4 __attribute__((ext_vector_type(4)));
typedef short bf8   __attribute__((ext_vector_type(8)));   // 8 bf16 (bit pattern)
typedef unsigned short u16;
typedef u16 u16x8 __attribute__((ext_vector_type(8)));
typedef u16 u16x4 __attribute__((ext_vector_type(4)));

__device__ __forceinline__ u16 f2bf(float x) {  // RNE f32->bf16
  unsigned int u = __float_as_uint(x);
  u += 0x7fffu + ((u >> 16) & 1u);
  return (u16)(u >> 16);
}

// Swizzled fragment read from a [R][64] bf16 LDS tile (XOR swizzle on 8-elem
// granularity). row = the M/N index; kc = starting k element (multiple of 8).
__device__ __forceinline__ bf8 ldfrag(const u16* t, int row, int kc) {
  return *(const bf8*)&t[row * 64 + (kc ^ ((row & 7) << 3))];
}

// ---------------------------------------------------------------------------
// Kernel 1: QKV projection GEMM. zi=0 -> q f32 [bh][s][d]; zi=1 -> K bf16
// [bh][s][d]; zi=2 -> V^T bf16 [bh][d][s].
// ---------------------------------------------------------------------------
__global__ __launch_bounds__(256) void qkv_gemm_kernel(
    const float* __restrict__ X,
    const float* __restrict__ Wq, const float* __restrict__ bq,
    const float* __restrict__ Wk, const float* __restrict__ bk,
    const float* __restrict__ Wv, const float* __restrict__ bv,
    float* __restrict__ qout, u16* __restrict__ kbout, u16* __restrict__ vtout) {
  const int zi = blockIdx.z;
  const float* __restrict__ W    = (zi == 0) ? Wq : (zi == 1 ? Wk : Wv);
  const float* __restrict__ bias = (zi == 0) ? bq : (zi == 1 ? bk : bv);

  const int bm = blockIdx.y * 64;
  const int bn = blockIdx.x * 64;
  const int tid = threadIdx.x;
  const int tx = tid & 15, ty = tid >> 4;

  __shared__ float As[16][68];
  __shared__ float Bs[16][68];

  float acc[4][4] = {};

  const int arow = tid >> 2;
  const int akc  = (tid & 3) << 2;
  const int brow = tid >> 4;
  const int bcol = (tid & 15) << 2;

  for (int k0 = 0; k0 < HIDD; k0 += 16) {
    float4 a4 = *(const float4*)&X[(size_t)(bm + arow) * HIDD + k0 + akc];
    float4 b4 = *(const float4*)&W[(size_t)(k0 + brow) * HIDD + bn + bcol];
    As[akc + 0][arow] = a4.x;
    As[akc + 1][arow] = a4.y;
    As[akc + 2][arow] = a4.z;
    As[akc + 3][arow] = a4.w;
    *(float4*)&Bs[brow][bcol] = b4;
    __syncthreads();
#pragma unroll
    for (int kk = 0; kk < 16; ++kk) {
      float4 av  = *(const float4*)&As[kk][ty << 2];
      float4 bv4 = *(const float4*)&Bs[kk][tx << 2];
      float a[4]  = {av.x, av.y, av.z, av.w};
      float bb[4] = {bv4.x, bv4.y, bv4.z, bv4.w};
#pragma unroll
      for (int i = 0; i < 4; ++i)
#pragma unroll
        for (int j = 0; j < 4; ++j) acc[i][j] = fmaf(a[i], bb[j], acc[i][j]);
    }
    __syncthreads();
  }

  const int h = bn >> 6;        // BN=64 == HD -> one head per block-column
  const int d0 = tx << 2;
  const int bidx = bm >> 10;
  const int sbase = (bm & 1023) + (ty << 2);

  if (zi == 0) {
#pragma unroll
    for (int i = 0; i < 4; ++i) {
      float4 o;
      o.x = acc[i][0] + bias[bn + d0 + 0];
      o.y = acc[i][1] + bias[bn + d0 + 1];
      o.z = acc[i][2] + bias[bn + d0 + 2];
      o.w = acc[i][3] + bias[bn + d0 + 3];
      *(float4*)&qout[(((size_t)(bidx * NHH + h)) * SS + sbase + i) * HDD + d0] = o;
    }
  } else if (zi == 1) {
#pragma unroll
    for (int i = 0; i < 4; ++i) {
      u16x4 kw;
#pragma unroll
      for (int j = 0; j < 4; ++j) kw[j] = f2bf(acc[i][j] + bias[bn + d0 + j]);
      *(u16x4*)&kbout[(((size_t)(bidx * NHH + h)) * SS + sbase + i) * HDD + d0] = kw;
    }
  } else {
#pragma unroll
    for (int j = 0; j < 4; ++j) {
      u16x4 vw;
      const float bj = bias[bn + d0 + j];
#pragma unroll
      for (int i = 0; i < 4; ++i) vw[i] = f2bf(acc[i][j] + bj);
      *(u16x4*)&vtout[(((size_t)(bidx * NHH + h)) * HDD + d0 + j) * SS + sbase] = vw;
    }
  }
}

// ---------------------------------------------------------------------------
// Kernel 1b: dist_emb f32 -> bf16 (once).
// ---------------------------------------------------------------------------
__global__ __launch_bounds__(256) void econv_kernel(const float* __restrict__ demb,
                                                    u16* __restrict__ eb) {
  int i = (blockIdx.x * 256 + threadIdx.x) * 8;
  if (i < 2047 * HDD) {
    float4 a = *(const float4*)&demb[i];
    float4 b = *(const float4*)&demb[i + 4];
    u16x8 o;
    o[0] = f2bf(a.x); o[1] = f2bf(a.y); o[2] = f2bf(a.z); o[3] = f2bf(a.w);
    o[4] = f2bf(b.x); o[5] = f2bf(b.y); o[6] = f2bf(b.z); o[7] = f2bf(b.w);
    *(u16x8*)&eb[i] = o;
  }
}

// ---------------------------------------------------------------------------
// Kernel 2: MFMA dual-branch flash attention with Toeplitz bias-as-GEMM.
// Block = 32 q-rows (2 waves, 16 rows each); K-tiles of 64.
// ---------------------------------------------------------------------------
__global__ __launch_bounds__(128) void attn_kernel(
    const float* __restrict__ q,     // [B*NH][S][64] f32
    const u16* __restrict__ kbg,     // [B*NH][S][64] bf16
    const u16* __restrict__ vtg,     // [B*NH][64][S] bf16
    const u16* __restrict__ eb,      // [2047][64] bf16
    const float* __restrict__ am,    // [B][S]
    const float* __restrict__ smask, // [S][S]
    const float* __restrict__ selp,  // [B][S]
    float* __restrict__ out) {       // [B][S][768]
  const int l0 = blockIdx.x * 32;
  const int h  = blockIdx.y;
  const int b  = blockIdx.z;
  const int bh = b * NHH + h;
  const size_t hoff = (size_t)bh * SS * HDD;

  __shared__ u16  ks[64 * 64];        // K tile   [r][d]  swizzled
  __shared__ u16  vs[64 * 64];        // V^T tile [d][r]  swizzled
  __shared__ u16  es[96 * 64];        // E window [j][d]  swizzled
  __shared__ float Tsc[2][16 * 84];   // per-wave bias GEMM result
  __shared__ u16  ps1[2][16 * 64];    // per-wave P (branch 1) swizzled
  __shared__ u16  ps2[2][16 * 64];    // per-wave P (branch 2) swizzled

  const int tid  = threadIdx.x;
  const int lane = tid & 63;
  const int w    = tid >> 6;
  const int g    = lane >> 4;
  const int ln   = lane & 15;

  // Q A-fragments (rows l0+16w+ln, k = 32*kk + 8g + b) held for all tiles
  bf8 qf[2];
  {
    const float* qp = q + hoff + (size_t)(l0 + 16 * w + ln) * HDD + g * 8;
#pragma unroll
    for (int kk = 0; kk < 2; ++kk) {
      float4 x = *(const float4*)(qp + kk * 32);
      float4 y = *(const float4*)(qp + kk * 32 + 4);
      bf8 f;
      f[0] = (short)f2bf(x.x); f[1] = (short)f2bf(x.y);
      f[2] = (short)f2bf(x.z); f[3] = (short)f2bf(x.w);
      f[4] = (short)f2bf(y.x); f[5] = (short)f2bf(y.y);
      f[6] = (short)f2bf(y.z); f[7] = (short)f2bf(y.w);
      qf[kk] = f;
    }
  }

  f32x4 acc1[4] = {}, acc2[4] = {};
  float m1[4], m2[4], sum1[4], sum2[4];
#pragma unroll
  for (int i = 0; i < 4; ++i) {
    m1[i] = -INFINITY; m2[i] = -INFINITY; sum1[i] = 0.f; sum2[i] = 0.f;
  }

  for (int t = 0; t < 16; ++t) {
    const int r0 = t * 64;
    __syncthreads();  // prev-iter LDS readers done
    {
      const int rr = tid >> 2;            // 0..31
      const int cc = (tid & 3) << 4;      // 0,16,32,48
      const u16* kgp = kbg + hoff + (size_t)r0 * HDD;
      const u16* vgp = vtg + hoff + r0;
#pragma unroll
      for (int p = 0; p < 2; ++p) {
        const int r = rr + 32 * p;
        const int sw = (r & 7) << 3;
        u16x8 a0 = *(const u16x8*)&kgp[(size_t)r * HDD + cc];
        u16x8 a1 = *(const u16x8*)&kgp[(size_t)r * HDD + cc + 8];
        *(u16x8*)&ks[r * 64 + (cc ^ sw)] = a0;
        *(u16x8*)&ks[r * 64 + ((cc + 8) ^ sw)] = a1;
        u16x8 c0 = *(const u16x8*)&vgp[(size_t)r * SS + cc];
        u16x8 c1 = *(const u16x8*)&vgp[(size_t)r * SS + cc + 8];
        *(u16x8*)&vs[r * 64 + (cc ^ sw)] = c0;
        *(u16x8*)&vs[r * 64 + ((cc + 8) ^ sw)] = c1;
      }
      const int ebase = l0 - r0 + 960;
#pragma unroll
      for (int p = 0; p < 3; ++p) {
        const int r = rr + 32 * p;        // 0..95
        const int gr = min(max(ebase + r, 0), 2046);
        const int sw = (r & 7) << 3;
        u16x8 a0 = *(const u16x8*)&eb[(size_t)gr * HDD + cc];
        u16x8 a1 = *(const u16x8*)&eb[(size_t)gr * HDD + cc + 8];
        *(u16x8*)&es[r * 64 + (cc ^ sw)] = a0;
        *(u16x8*)&es[r * 64 + ((cc + 8) ^ sw)] = a1;
      }
    }
    __syncthreads();

    // prefetch masks (L2/L3-resident)
    float amv[4], smv[4][4];
#pragma unroll
    for (int ct = 0; ct < 4; ++ct) {
      amv[ct] = am[(b << 10) + r0 + 16 * ct + ln];
#pragma unroll
      for (int i = 0; i < 4; ++i)
        smv[ct][i] = smask[(size_t)(l0 + 16 * w + 4 * g + i) * SS + r0 + 16 * ct + ln];
    }

    // QK^T: 16x64 scores
    f32x4 sc[4];
#pragma unroll
    for (int ct = 0; ct < 4; ++ct) {
      f32x4 x = {0.f, 0.f, 0.f, 0.f};
#pragma unroll
      for (int kk = 0; kk < 2; ++kk)
        x = __builtin_amdgcn_mfma_f32_16x16x32_bf16(
            qf[kk], ldfrag(ks, ct * 16 + ln, kk * 32 + g * 8), x, 0, 0, 0);
      sc[ct] = x;
    }

    // T = Q @ E_window^T (16x80), write to per-wave scratch
    float* Tw = &Tsc[w][0];
#pragma unroll
    for (int c5 = 0; c5 < 5; ++c5) {
      f32x4 x = {0.f, 0.f, 0.f, 0.f};
#pragma unroll
      for (int kk = 0; kk < 2; ++kk)
        x = __builtin_amdgcn_mfma_f32_16x16x32_bf16(
            qf[kk], ldfrag(es, 16 * w + c5 * 16 + ln, kk * 32 + g * 8), x, 0, 0, 0);
#pragma unroll
      for (int i = 0; i < 4; ++i) Tw[(4 * g + i) * 84 + c5 * 16 + ln] = x[i];
    }

    // gather bias, scores, dual online softmax
    u16* p1w = &ps1[w][0];
    u16* p2w = &ps2[w][0];
#pragma unroll
    for (int i = 0; i < 4; ++i) {
      const int ll = 4 * g + i;
      float s1r[4], s2r[4];
#pragma unroll
      for (int ct = 0; ct < 4; ++ct) {
        const int c = 16 * ct + ln;
        const float tb = Tw[ll * 84 + (ll + 63 - c)];
        const float s1 = (sc[ct][i] + tb) * 0.125f + amv[ct];
        s1r[ct] = s1;
        s2r[ct] = s1 * smv[ct][i] + amv[ct];
      }
      // branch 1
      {
        float mx = fmaxf(fmaxf(s1r[0], s1r[1]), fmaxf(s1r[2], s1r[3]));
#pragma unroll
        for (int off = 1; off < 16; off <<= 1) mx = fmaxf(mx, __shfl_xor(mx, off, 64));
        const float mn = fmaxf(m1[i], mx);
        const float scale = __expf(m1[i] - mn);
        float rs = 0.f;
#pragma unroll
        for (int ct = 0; ct < 4; ++ct) {
          const float p = __expf(s1r[ct] - mn);
          const int c = 16 * ct + ln;
          p1w[ll * 64 + (c ^ ((ll & 7) << 3))] = f2bf(p);
          rs += p;
        }
#pragma unroll
        for (int off = 1; off < 16; off <<= 1) rs += __shfl_xor(rs, off, 64);
        sum1[i] = sum1[i] * scale + rs;
        m1[i] = mn;
#pragma unroll
        for (int dt = 0; dt < 4; ++dt) acc1[dt][i] *= scale;
      }
      // branch 2
      {
        float mx = fmaxf(fmaxf(s2r[0], s2r[1]), fmaxf(s2r[2], s2r[3]));
#pragma unroll
        for (int off = 1; off < 16; off <<= 1) mx = fmaxf(mx, __shfl_xor(mx, off, 64));
        const float mn = fmaxf(m2[i], mx);
        const float scale = __expf(m2[i] - mn);
        float rs = 0.f;
#pragma unroll
        for (int ct = 0; ct < 4; ++ct) {
          const float p = __expf(s2r[ct] - mn);
          const int c = 16 * ct + ln;
          p2w[ll * 64 + (c ^ ((ll & 7) << 3))] = f2bf(p);
          rs += p;
        }
#pragma unroll
        for (int off = 1; off < 16; off <<= 1) rs += __shfl_xor(rs, off, 64);
        sum2[i] = sum2[i] * scale + rs;
        m2[i] = mn;
#pragma unroll
        for (int dt = 0; dt < 4; ++dt) acc2[dt][i] *= scale;
      }
    }

    // PV for both branches (shared V fragments)
#pragma unroll
    for (int kk = 0; kk < 2; ++kk) {
      bf8 pa = ldfrag(p1w, ln, kk * 32 + g * 8);
      bf8 pb = ldfrag(p2w, ln, kk * 32 + g * 8);
#pragma unroll
      for (int dt = 0; dt < 4; ++dt) {
        bf8 vb = ldfrag(vs, dt * 16 + ln, kk * 32 + g * 8);
        acc1[dt] = __builtin_amdgcn_mfma_f32_16x16x32_bf16(pa, vb, acc1[dt], 0, 0, 0);
        acc2[dt] = __builtin_amdgcn_mfma_f32_16x16x32_bf16(pb, vb, acc2[dt], 0, 0, 0);
      }
    }
  }

  // epilogue
#pragma unroll
  for (int i = 0; i < 4; ++i) {
    const int lg = l0 + 16 * w + 4 * g + i;
    const float se = selp[(b << 10) + lg];
    const float inv1 = 1.f / sum1[i];
    const float inv2 = 1.f / sum2[i];
#pragma unroll
    for (int dt = 0; dt < 4; ++dt) {
      const float o = se * (acc2[dt][i] * inv2) + (1.f - se) * (acc1[dt][i] * inv1);
      out[((size_t)((b << 10) + lg)) * HIDD + h * HDD + dt * 16 + ln] = o;
    }
  }
}

extern "C" void kernel_launch(void* const* d_in, const int* in_sizes, int n_in,
                              void* d_out, int out_size, void* d_ws, size_t ws_size,
                              hipStream_t stream) {
  const float* hidden = (const float*)d_in[0];
  const float* am     = (const float*)d_in[1];
  const float* smask  = (const float*)d_in[2];
  const float* selp   = (const float*)d_in[3];
  const float* Wq     = (const float*)d_in[4];
  const float* bq     = (const float*)d_in[5];
  const float* Wk     = (const float*)d_in[6];
  const float* bk     = (const float*)d_in[7];
  const float* Wv     = (const float*)d_in[8];
  const float* bv     = (const float*)d_in[9];
  const float* demb   = (const float*)d_in[10];
  float* out = (float*)d_out;

  float* ws = (float*)d_ws;
  const size_t NEL = (size_t)BB * NHH * SS * HDD;  // 1572864
  float* qws = ws;                                 // f32
  u16* kbw = (u16*)(ws + NEL);
  u16* vtw = kbw + NEL;
  u16* ebw = vtw + NEL;                            // 2047*64 u16

  econv_kernel<<<64, 256, 0, stream>>>(demb, ebw);

  dim3 g1(HIDD / 64, (BB * SS) / 64, 3);
  qkv_gemm_kernel<<<g1, 256, 0, stream>>>(hidden, Wq, bq, Wk, bk, Wv, bv,
                                          qws, kbw, vtw);

  dim3 g2(SS / 32, NHH, BB);
  attn_kernel<<<g2, 128, 0, stream>>>(qws, kbw, vtw, ebw, am, smask, selp, out);
}

// Round 3
// 100.915 us; speedup vs baseline: 7.4242x; 2.0850x over previous
//
#include <hip/hip_runtime.h>
#include <hip/hip_bf16.h>
#include <math.h>

#define BB   2
#define SS   1024
#define HIDD 768
#define NHH  12
#define HDD  64

typedef float f32x4 __attribute__((ext_vector_type(4)));
typedef short bf8   __attribute__((ext_vector_type(8)));   // 8 bf16 (bit pattern)
typedef unsigned short u16;
typedef u16 u16x8 __attribute__((ext_vector_type(8)));
typedef u16 u16x4 __attribute__((ext_vector_type(4)));

__device__ __forceinline__ u16 f2bf(float x) {  // RNE f32->bf16
  unsigned int u = __float_as_uint(x);
  u += 0x7fffu + ((u >> 16) & 1u);
  return (u16)(u >> 16);
}

// Swizzled fragment read from a [R][64] bf16 LDS tile (XOR swizzle, 8-elem
// granularity). row = M/N index; kc = starting k element (multiple of 8).
__device__ __forceinline__ bf8 ldfrag(const u16* t, int row, int kc) {
  return *(const bf8*)&t[row * 64 + (kc ^ ((row & 7) << 3))];
}

// ---------------------------------------------------------------------------
// Prep: X f32 -> bf16 (same layout).
// ---------------------------------------------------------------------------
__global__ __launch_bounds__(256) void xconv_kernel(const float* __restrict__ X,
                                                    u16* __restrict__ Xb) {
  int i = (blockIdx.x * 256 + threadIdx.x) * 8;
  float4 a = *(const float4*)&X[i];
  float4 b = *(const float4*)&X[i + 4];
  u16x8 o;
  o[0] = f2bf(a.x); o[1] = f2bf(a.y); o[2] = f2bf(a.z); o[3] = f2bf(a.w);
  o[4] = f2bf(b.x); o[5] = f2bf(b.y); o[6] = f2bf(b.z); o[7] = f2bf(b.w);
  *(u16x8*)&Xb[i] = o;
}

// ---------------------------------------------------------------------------
// Prep: W [k][n] f32 (x3) -> Wt [3*768 rows n][768 cols k] bf16 (transposed).
// ---------------------------------------------------------------------------
__global__ __launch_bounds__(256) void wtconv_kernel(
    const float* __restrict__ Wq, const float* __restrict__ Wk,
    const float* __restrict__ Wv, u16* __restrict__ Wt) {
  const int zi = blockIdx.z;
  const float* __restrict__ W = (zi == 0) ? Wq : (zi == 1 ? Wk : Wv);
  const int n0 = blockIdx.x * 64;
  const int k0 = blockIdx.y * 64;
  __shared__ float t[64][65];
  const int tid = threadIdx.x;
  {
    const int kl = tid >> 4;
    const int nl = (tid & 15) * 4;
#pragma unroll
    for (int p = 0; p < 4; ++p) {
      float4 v = *(const float4*)&W[(size_t)(k0 + kl + 16 * p) * HIDD + n0 + nl];
      t[kl + 16 * p][nl + 0] = v.x;
      t[kl + 16 * p][nl + 1] = v.y;
      t[kl + 16 * p][nl + 2] = v.z;
      t[kl + 16 * p][nl + 3] = v.w;
    }
  }
  __syncthreads();
  {
    const int nl = tid >> 4;
    const int cl = (tid & 15) * 4;
#pragma unroll
    for (int p = 0; p < 4; ++p) {
      const int n = nl + 16 * p;
      u16x4 o;
      o[0] = f2bf(t[cl + 0][n]);
      o[1] = f2bf(t[cl + 1][n]);
      o[2] = f2bf(t[cl + 2][n]);
      o[3] = f2bf(t[cl + 3][n]);
      *(u16x4*)&Wt[(size_t)(zi * HIDD + n0 + n) * HIDD + k0 + cl] = o;
    }
  }
}

// ---------------------------------------------------------------------------
// Prep: dist_emb f32 -> bf16.
// ---------------------------------------------------------------------------
__global__ __launch_bounds__(256) void econv_kernel(const float* __restrict__ demb,
                                                    u16* __restrict__ eb) {
  int i = (blockIdx.x * 256 + threadIdx.x) * 8;
  if (i < 2047 * HDD) {
    float4 a = *(const float4*)&demb[i];
    float4 b = *(const float4*)&demb[i + 4];
    u16x8 o;
    o[0] = f2bf(a.x); o[1] = f2bf(a.y); o[2] = f2bf(a.z); o[3] = f2bf(a.w);
    o[4] = f2bf(b.x); o[5] = f2bf(b.y); o[6] = f2bf(b.z); o[7] = f2bf(b.w);
    *(u16x8*)&eb[i] = o;
  }
}

// ---------------------------------------------------------------------------
// Fused QKV MFMA GEMM: [2048,768]bf16 @ Wt^T -> N=2304 (Q|K|V).
// 128x128 tile, BK=64, 4 waves (2x2), wave tile 64x64.
// Q,K epilogue: swapped-operand (transposed frags) -> row-major [bh][s][d].
// V epilogue: normal order -> V^T [bh][d][s].
// ---------------------------------------------------------------------------
__global__ __launch_bounds__(256) void qkv_mfma_kernel(
    const u16* __restrict__ Xb,   // [2048][768]
    const u16* __restrict__ Wt,   // [2304][768]
    const float* __restrict__ bq, const float* __restrict__ bk,
    const float* __restrict__ bv,
    u16* __restrict__ qb, u16* __restrict__ kb, u16* __restrict__ vt) {
  const int bn = blockIdx.x;   // 0..17
  const int bm = blockIdx.y;   // 0..15
  const int zi = bn / 6;

  __shared__ u16 As[128 * 64];
  __shared__ u16 Bs[128 * 64];

  const int tid  = threadIdx.x;
  const int lane = tid & 63;
  const int w    = tid >> 6;
  const int g    = lane >> 4;
  const int ln   = lane & 15;
  const int wm   = (w >> 1) * 64;
  const int wn   = (w & 1) * 64;

  f32x4 acc[4][4] = {};

  const int srow = tid >> 3;        // 0..31
  const int scol = (tid & 7) * 8;   // 0..56
  const u16* Ag = Xb + (size_t)(bm * 128 + srow) * HIDD + scol;
  const u16* Bg = Wt + (size_t)(bn * 128 + srow) * HIDD + scol;

  for (int k0 = 0; k0 < HIDD; k0 += 64) {
    if (k0) __syncthreads();
#pragma unroll
    for (int p = 0; p < 4; ++p) {
      const int r = srow + 32 * p;
      const int sw = (r & 7) << 3;
      *(u16x8*)&As[r * 64 + (scol ^ sw)] =
          *(const u16x8*)&Ag[(size_t)(32 * p) * HIDD + k0];
      *(u16x8*)&Bs[r * 64 + (scol ^ sw)] =
          *(const u16x8*)&Bg[(size_t)(32 * p) * HIDD + k0];
    }
    __syncthreads();

    bf8 af[4][2], bfr[4][2];
#pragma unroll
    for (int f = 0; f < 4; ++f)
#pragma unroll
      for (int kk = 0; kk < 2; ++kk) {
        af[f][kk]  = ldfrag(As, wm + 16 * f + ln, kk * 32 + g * 8);
        bfr[f][kk] = ldfrag(Bs, wn + 16 * f + ln, kk * 32 + g * 8);
      }
    if (zi < 2) {  // transposed output frags
#pragma unroll
      for (int mf = 0; mf < 4; ++mf)
#pragma unroll
        for (int nf = 0; nf < 4; ++nf)
#pragma unroll
          for (int kk = 0; kk < 2; ++kk)
            acc[mf][nf] = __builtin_amdgcn_mfma_f32_16x16x32_bf16(
                bfr[nf][kk], af[mf][kk], acc[mf][nf], 0, 0, 0);
    } else {
#pragma unroll
      for (int mf = 0; mf < 4; ++mf)
#pragma unroll
        for (int nf = 0; nf < 4; ++nf)
#pragma unroll
          for (int kk = 0; kk < 2; ++kk)
            acc[mf][nf] = __builtin_amdgcn_mfma_f32_16x16x32_bf16(
                af[mf][kk], bfr[nf][kk], acc[mf][nf], 0, 0, 0);
    }
  }

  const int mrow  = bm * 128 + wm;
  const int nbase = (bn % 6) * 128 + wn;  // 0..767 within zi, multiple of 64
  const int h     = nbase >> 6;

  if (zi < 2) {
    const float* __restrict__ bias = zi ? bk : bq;
    u16* __restrict__ outp = zi ? kb : qb;
#pragma unroll
    for (int nf = 0; nf < 4; ++nf) {
      const int d0 = 16 * nf + 4 * g;           // d within head
      float4 bi = *(const float4*)&bias[nbase + d0];
#pragma unroll
      for (int mf = 0; mf < 4; ++mf) {
        const int m = mrow + 16 * mf + ln;      // token index
        const int b = m >> 10, s = m & 1023;
        u16x4 o;
        o[0] = f2bf(acc[mf][nf][0] + bi.x);
        o[1] = f2bf(acc[mf][nf][1] + bi.y);
        o[2] = f2bf(acc[mf][nf][2] + bi.z);
        o[3] = f2bf(acc[mf][nf][3] + bi.w);
        *(u16x4*)&outp[(((size_t)(b * NHH + h)) * SS + s) * HDD + d0] = o;
      }
    }
  } else {
#pragma unroll
    for (int nf = 0; nf < 4; ++nf) {
      const int d = 16 * nf + ln;
      const float bi = bv[nbase + d];
#pragma unroll
      for (int mf = 0; mf < 4; ++mf) {
        const int m = mrow + 16 * mf + 4 * g;   // 4 consecutive tokens
        const int b = m >> 10, s = m & 1023;
        u16x4 o;
        o[0] = f2bf(acc[mf][nf][0] + bi);
        o[1] = f2bf(acc[mf][nf][1] + bi);
        o[2] = f2bf(acc[mf][nf][2] + bi);
        o[3] = f2bf(acc[mf][nf][3] + bi);
        *(u16x4*)&vt[(((size_t)(b * NHH + h)) * HDD + d) * SS + s] = o;
      }
    }
  }
}

// ---------------------------------------------------------------------------
// MFMA dual-branch flash attention with Toeplitz bias-as-GEMM.
// Block = 32 q-rows (2 waves, 16 rows each); K-tiles of 64.
// ---------------------------------------------------------------------------
__global__ __launch_bounds__(128) void attn_kernel(
    const u16* __restrict__ qbg,     // [B*NH][S][64] bf16
    const u16* __restrict__ kbg,     // [B*NH][S][64] bf16
    const u16* __restrict__ vtg,     // [B*NH][64][S] bf16
    const u16* __restrict__ eb,      // [2047][64] bf16
    const float* __restrict__ am,    // [B][S]
    const float* __restrict__ smask, // [S][S]
    const float* __restrict__ selp,  // [B][S]
    float* __restrict__ out) {       // [B][S][768]
  const int l0 = blockIdx.x * 32;
  const int h  = blockIdx.y;
  const int b  = blockIdx.z;
  const int bh = b * NHH + h;
  const size_t hoff = (size_t)bh * SS * HDD;

  __shared__ u16  ks[64 * 64];        // K tile   [r][d]  swizzled
  __shared__ u16  vs[64 * 64];        // V^T tile [d][r]  swizzled
  __shared__ u16  es[96 * 64];        // E window [j][d]  swizzled
  __shared__ float Tsc[2][16 * 84];   // per-wave bias GEMM result
  __shared__ u16  ps1[2][16 * 64];    // per-wave P (branch 1) swizzled
  __shared__ u16  ps2[2][16 * 64];    // per-wave P (branch 2) swizzled

  const int tid  = threadIdx.x;
  const int lane = tid & 63;
  const int w    = tid >> 6;
  const int g    = lane >> 4;
  const int ln   = lane & 15;

  // Q A-fragments (rows l0+16w+ln, k = 32*kk + 8g + j), bf16 direct
  bf8 qf[2];
  {
    const u16* qp = qbg + hoff + (size_t)(l0 + 16 * w + ln) * HDD + g * 8;
    qf[0] = *(const bf8*)(qp);
    qf[1] = *(const bf8*)(qp + 32);
  }

  f32x4 acc1[4] = {}, acc2[4] = {};
  float m1[4], m2[4], sum1[4], sum2[4];
#pragma unroll
  for (int i = 0; i < 4; ++i) {
    m1[i] = -INFINITY; m2[i] = -INFINITY; sum1[i] = 0.f; sum2[i] = 0.f;
  }

  for (int t = 0; t < 16; ++t) {
    const int r0 = t * 64;
    __syncthreads();  // prev-iter LDS readers done
    {
      const int rr = tid >> 2;            // 0..31
      const int cc = (tid & 3) << 4;      // 0,16,32,48
      const u16* kgp = kbg + hoff + (size_t)r0 * HDD;
      const u16* vgp = vtg + hoff + r0;
#pragma unroll
      for (int p = 0; p < 2; ++p) {
        const int r = rr + 32 * p;
        const int sw = (r & 7) << 3;
        u16x8 a0 = *(const u16x8*)&kgp[(size_t)r * HDD + cc];
        u16x8 a1 = *(const u16x8*)&kgp[(size_t)r * HDD + cc + 8];
        *(u16x8*)&ks[r * 64 + (cc ^ sw)] = a0;
        *(u16x8*)&ks[r * 64 + ((cc + 8) ^ sw)] = a1;
        u16x8 c0 = *(const u16x8*)&vgp[(size_t)r * SS + cc];
        u16x8 c1 = *(const u16x8*)&vgp[(size_t)r * SS + cc + 8];
        *(u16x8*)&vs[r * 64 + (cc ^ sw)] = c0;
        *(u16x8*)&vs[r * 64 + ((cc + 8) ^ sw)] = c1;
      }
      const int ebase = l0 - r0 + 960;
#pragma unroll
      for (int p = 0; p < 3; ++p) {
        const int r = rr + 32 * p;        // 0..95
        const int gr = min(max(ebase + r, 0), 2046);
        const int sw = (r & 7) << 3;
        u16x8 a0 = *(const u16x8*)&eb[(size_t)gr * HDD + cc];
        u16x8 a1 = *(const u16x8*)&eb[(size_t)gr * HDD + cc + 8];
        *(u16x8*)&es[r * 64 + (cc ^ sw)] = a0;
        *(u16x8*)&es[r * 64 + ((cc + 8) ^ sw)] = a1;
      }
    }
    __syncthreads();

    // prefetch masks (L2/L3-resident)
    float amv[4], smv[4][4];
#pragma unroll
    for (int ct = 0; ct < 4; ++ct) {
      amv[ct] = am[(b << 10) + r0 + 16 * ct + ln];
#pragma unroll
      for (int i = 0; i < 4; ++i)
        smv[ct][i] = smask[(size_t)(l0 + 16 * w + 4 * g + i) * SS + r0 + 16 * ct + ln];
    }

    // QK^T: 16x64 scores
    f32x4 sc[4];
    __builtin_amdgcn_s_setprio(1);
#pragma unroll
    for (int ct = 0; ct < 4; ++ct) {
      f32x4 x = {0.f, 0.f, 0.f, 0.f};
#pragma unroll
      for (int kk = 0; kk < 2; ++kk)
        x = __builtin_amdgcn_mfma_f32_16x16x32_bf16(
            qf[kk], ldfrag(ks, ct * 16 + ln, kk * 32 + g * 8), x, 0, 0, 0);
      sc[ct] = x;
    }

    // T = Q @ E_window^T (16x80), write to per-wave scratch
    float* Tw = &Tsc[w][0];
#pragma unroll
    for (int c5 = 0; c5 < 5; ++c5) {
      f32x4 x = {0.f, 0.f, 0.f, 0.f};
#pragma unroll
      for (int kk = 0; kk < 2; ++kk)
        x = __builtin_amdgcn_mfma_f32_16x16x32_bf16(
            qf[kk], ldfrag(es, 16 * w + c5 * 16 + ln, kk * 32 + g * 8), x, 0, 0, 0);
#pragma unroll
      for (int i = 0; i < 4; ++i) Tw[(4 * g + i) * 84 + c5 * 16 + ln] = x[i];
    }
    __builtin_amdgcn_s_setprio(0);

    // gather bias, scores, dual online softmax
    u16* p1w = &ps1[w][0];
    u16* p2w = &ps2[w][0];
#pragma unroll
    for (int i = 0; i < 4; ++i) {
      const int ll = 4 * g + i;
      float s1r[4], s2r[4];
#pragma unroll
      for (int ct = 0; ct < 4; ++ct) {
        const int c = 16 * ct + ln;
        const float tb = Tw[ll * 84 + (ll + 63 - c)];
        const float s1 = (sc[ct][i] + tb) * 0.125f + amv[ct];
        s1r[ct] = s1;
        s2r[ct] = s1 * smv[ct][i] + amv[ct];
      }
      // branch 1
      {
        float mx = fmaxf(fmaxf(s1r[0], s1r[1]), fmaxf(s1r[2], s1r[3]));
#pragma unroll
        for (int off = 1; off < 16; off <<= 1) mx = fmaxf(mx, __shfl_xor(mx, off, 64));
        const float mn = fmaxf(m1[i], mx);
        const float scale = __expf(m1[i] - mn);
        float rs = 0.f;
#pragma unroll
        for (int ct = 0; ct < 4; ++ct) {
          const float p = __expf(s1r[ct] - mn);
          const int c = 16 * ct + ln;
          p1w[ll * 64 + (c ^ ((ll & 7) << 3))] = f2bf(p);
          rs += p;
        }
#pragma unroll
        for (int off = 1; off < 16; off <<= 1) rs += __shfl_xor(rs, off, 64);
        sum1[i] = sum1[i] * scale + rs;
        m1[i] = mn;
#pragma unroll
        for (int dt = 0; dt < 4; ++dt) acc1[dt][i] *= scale;
      }
      // branch 2
      {
        float mx = fmaxf(fmaxf(s2r[0], s2r[1]), fmaxf(s2r[2], s2r[3]));
#pragma unroll
        for (int off = 1; off < 16; off <<= 1) mx = fmaxf(mx, __shfl_xor(mx, off, 64));
        const float mn = fmaxf(m2[i], mx);
        const float scale = __expf(m2[i] - mn);
        float rs = 0.f;
#pragma unroll
        for (int ct = 0; ct < 4; ++ct) {
          const float p = __expf(s2r[ct] - mn);
          const int c = 16 * ct + ln;
          p2w[ll * 64 + (c ^ ((ll & 7) << 3))] = f2bf(p);
          rs += p;
        }
#pragma unroll
        for (int off = 1; off < 16; off <<= 1) rs += __shfl_xor(rs, off, 64);
        sum2[i] = sum2[i] * scale + rs;
        m2[i] = mn;
#pragma unroll
        for (int dt = 0; dt < 4; ++dt) acc2[dt][i] *= scale;
      }
    }
    // NOTE: no barrier here — ps1/ps2 are wave-private; same-wave LDS
    // write->read ordering is handled by lgkmcnt.

    // PV for both branches (shared V fragments)
    __builtin_amdgcn_s_setprio(1);
#pragma unroll
    for (int kk = 0; kk < 2; ++kk) {
      bf8 pa = ldfrag(p1w, ln, kk * 32 + g * 8);
      bf8 pb = ldfrag(p2w, ln, kk * 32 + g * 8);
#pragma unroll
      for (int dt = 0; dt < 4; ++dt) {
        bf8 vb = ldfrag(vs, dt * 16 + ln, kk * 32 + g * 8);
        acc1[dt] = __builtin_amdgcn_mfma_f32_16x16x32_bf16(pa, vb, acc1[dt], 0, 0, 0);
        acc2[dt] = __builtin_amdgcn_mfma_f32_16x16x32_bf16(pb, vb, acc2[dt], 0, 0, 0);
      }
    }
    __builtin_amdgcn_s_setprio(0);
  }

  // epilogue
#pragma unroll
  for (int i = 0; i < 4; ++i) {
    const int lg = l0 + 16 * w + 4 * g + i;
    const float se = selp[(b << 10) + lg];
    const float inv1 = 1.f / sum1[i];
    const float inv2 = 1.f / sum2[i];
#pragma unroll
    for (int dt = 0; dt < 4; ++dt) {
      const float o = se * (acc2[dt][i] * inv2) + (1.f - se) * (acc1[dt][i] * inv1);
      out[((size_t)((b << 10) + lg)) * HIDD + h * HDD + dt * 16 + ln] = o;
    }
  }
}

extern "C" void kernel_launch(void* const* d_in, const int* in_sizes, int n_in,
                              void* d_out, int out_size, void* d_ws, size_t ws_size,
                              hipStream_t stream) {
  const float* hidden = (const float*)d_in[0];
  const float* am     = (const float*)d_in[1];
  const float* smask  = (const float*)d_in[2];
  const float* selp   = (const float*)d_in[3];
  const float* Wq     = (const float*)d_in[4];
  const float* bq     = (const float*)d_in[5];
  const float* Wk     = (const float*)d_in[6];
  const float* bk     = (const float*)d_in[7];
  const float* Wv     = (const float*)d_in[8];
  const float* bv     = (const float*)d_in[9];
  const float* demb   = (const float*)d_in[10];
  float* out = (float*)d_out;

  u16* wsp = (u16*)d_ws;
  const size_t NEL = (size_t)BB * NHH * SS * HDD;  // 1572864
  u16* Xb  = wsp;                    // 2048*768
  u16* Wt  = Xb + (size_t)2048 * HIDD;   // 2304*768
  u16* qbw = Wt + (size_t)3 * HIDD * HIDD;
  u16* kbw = qbw + NEL;
  u16* vtw = kbw + NEL;
  u16* ebw = vtw + NEL;              // 2047*64

  xconv_kernel<<<768, 256, 0, stream>>>(hidden, Xb);
  dim3 gw(HIDD / 64, HIDD / 64, 3);
  wtconv_kernel<<<gw, 256, 0, stream>>>(Wq, Wk, Wv, Wt);
  econv_kernel<<<64, 256, 0, stream>>>(demb, ebw);

  dim3 g1(18, 16);
  qkv_mfma_kernel<<<g1, 256, 0, stream>>>(Xb, Wt, bq, bk, bv, qbw, kbw, vtw);

  dim3 g2(SS / 32, NHH, BB);
  attn_kernel<<<g2, 128, 0, stream>>>(qbw, kbw, vtw, ebw, am, smask, selp, out);
}